// Round 1
// baseline (359.822 us; speedup 1.0000x reference)
//
#include <hip/hip_runtime.h>

// CausalLinearRelativeAttention — chunked 3-branch causal linear attention, bf16 MFMA.
// N=4, L=2048, H=8, D=Dv=128, chunk C=128, T=16 chunks, 3 branches (coeff -2 folded into Qb2).

typedef float f32x4 __attribute__((ext_vector_type(4)));
typedef short s16x8 __attribute__((ext_vector_type(8)));
typedef unsigned short u16;

static constexpr int    Ln   = 2048;
static constexpr size_t NHLD = (size_t)32 * 2048 * 128; // per-branch feature array elems = 8,388,608

__device__ __forceinline__ float b2f(u16 s) {
  union { unsigned u; float f; } x; x.u = ((unsigned)s) << 16; return x.f;
}
__device__ __forceinline__ u16 f2b(float f) {
  union { float f; unsigned u; } x; x.f = f;
  unsigned r = x.u + 0x7fffu + ((x.u >> 16) & 1u);
  return (u16)(r >> 16);
}

// ---------------------------------------------------------------- K0: omega^T (bf16) + column sums
__global__ __launch_bounds__(256) void k_omega(const float* __restrict__ om,
                                               u16* __restrict__ wt, float* __restrict__ osum) {
  __shared__ alignas(16) u16 T[128][136];
  int h = blockIdx.x, t = threadIdx.x;
  for (int idx = t; idx < 128 * 32; idx += 256) {
    int i = idx >> 5, cs = (idx & 31) << 2;
    float4 vv = *(const float4*)(om + ((size_t)(h * 128 + i)) * 128 + cs);
    T[i][cs + 0] = f2b(vv.x); T[i][cs + 1] = f2b(vv.y);
    T[i][cs + 2] = f2b(vv.z); T[i][cs + 3] = f2b(vv.w);
  }
  if (t < 128) { // exact fp32 column sums from global (coalesced per row)
    float acc = 0.f;
    for (int i = 0; i < 128; i++) acc += om[((size_t)(h * 128 + i)) * 128 + t];
    osum[h * 128 + t] = acc;
  }
  __syncthreads();
  { // transposed write: wt[h][j][i] = omega[h][i][j]
    int j = t >> 1, lh = (t & 1) << 6;
    s16x8* dst = (s16x8*)(wt + ((size_t)(h * 128 + j)) * 128 + lh);
    for (int u = 0; u < 8; u++) {
      s16x8 pv;
#pragma unroll
      for (int e = 0; e < 8; e++) pv[e] = (short)T[lh + u * 8 + e][j];
      dst[u] = pv;
    }
  }
}

// ------------------------------------------- K1: proj = q2 @ omega (MFMA), fused Q-feature epilogue
// writes qb3[b][n][h][l][i], b-weights {s^2, c^2, -2sc}
__global__ __launch_bounds__(256) void k_qfeat(const float* __restrict__ q2g, const float* __restrict__ qg,
                                               const u16* __restrict__ wt, const float* __restrict__ osum,
                                               u16* __restrict__ qb3) {
  __shared__ alignas(16) u16 A[64][136];   // q2 tile (bf16), rows l, cols i
  __shared__ alignas(16) u16 B[128][136];  // omega^T[h], rows j, cols i
  __shared__ float osb[128];
  int bid = blockIdx.x, t = threadIdx.x;
  int m = bid & 31, h = (bid >> 5) & 7, n = bid >> 8;
  int l0 = m << 6, nh = (n << 3) + h;
  if (t < 128) osb[t] = osum[h * 128 + t];
  for (int idx = t; idx < 64 * 32; idx += 256) {
    int l = idx >> 5, cs = (idx & 31) << 2;
    float4 vv = *(const float4*)(q2g + (((size_t)(n * Ln + l0 + l) * 8 + h) << 7) + cs);
    A[l][cs + 0] = f2b(vv.x); A[l][cs + 1] = f2b(vv.y);
    A[l][cs + 2] = f2b(vv.z); A[l][cs + 3] = f2b(vv.w);
  }
  for (int idx = t; idx < 128 * 16; idx += 256) {
    int j = idx >> 4, cs = (idx & 15) << 3;
    *(s16x8*)&B[j][cs] = *(const s16x8*)(wt + ((size_t)(h * 128 + j)) * 128 + cs);
  }
  __syncthreads();
  int lane = t & 63, quad = lane >> 4, nl = lane & 15, w = t >> 6;
  f32x4 z4 = {0.f, 0.f, 0.f, 0.f};
  f32x4 acc[8];
#pragma unroll
  for (int i = 0; i < 8; i++) acc[i] = z4;
  for (int ks = 0; ks < 4; ks++) {
    int k0 = (ks << 5) + (quad << 3);
    s16x8 av = *(const s16x8*)&A[(w << 4) + nl][k0];
#pragma unroll
    for (int ct = 0; ct < 8; ct++) {
      s16x8 bv = *(const s16x8*)&B[(ct << 4) + nl][k0];
      acc[ct] = __builtin_amdgcn_mfma_f32_16x16x32_bf16(av, bv, acc[ct], 0, 0, 0);
    }
  }
  const float invL = 1.0f / 2048.0f;
  int lbase = (w << 4) + (quad << 2);
#pragma unroll
  for (int ct = 0; ct < 8; ct++) {
    int j = (ct << 4) + nl;
#pragma unroll
    for (int r = 0; r < 4; r++) {
      int l = lbase + r;
      float proj = acc[ct][r];
      float qv = qg[(((size_t)(n * Ln + l0 + l) * 8 + h) << 7) + j];
      float f = qv > 0.f ? qv + 1.f : __expf(qv); // elu(x)+1
      float sp = __sinf(proj);
      float Qt = sp * sp * f;
      float tt = (float)(l0 + l) * invL * osb[j];
      float s, c; __sincosf(tt, &s, &c);
      size_t base = ((size_t)nh * Ln + (l0 + l)) * 128 + j;
      qb3[base]            = f2b(Qt * s * s);
      qb3[base + NHLD]     = f2b(Qt * c * c);
      qb3[base + 2 * NHLD] = f2b(-2.f * Qt * s * c);
    }
  }
}

// ---------------------- K2: K features (natural kb3 + transposed kbt3), V transposed (vt), via LDS
// kb3 b-weights {c^2, s^2, sc}
__global__ __launch_bounds__(256) void k_kvfeat(const float* __restrict__ kg, const float* __restrict__ vg,
                                                const float* __restrict__ klg, const float* __restrict__ osum,
                                                u16* __restrict__ kb3, u16* __restrict__ kbt3,
                                                u16* __restrict__ vt) {
  __shared__ alignas(16) u16 Bu[4][32][136]; // Kb0,Kb1,Kb2,V strip tiles
  __shared__ float osb[128];
  int bid = blockIdx.x, t = threadIdx.x;
  int lt = bid & 15, h = (bid >> 4) & 7, n = bid >> 7;
  int l0 = lt << 7, nh = (n << 3) + h;
  const float invL = 1.0f / 2048.0f;
  if (t < 128) osb[t] = osum[h * 128 + t];
  for (int strip = 0; strip < 4; strip++) {
    int ls0 = strip << 5;
    __syncthreads();
    for (int idx = t; idx < 1024; idx += 256) {
      int rr = idx >> 5, cs = (idx & 31) << 2;
      int l = l0 + ls0 + rr;
      size_t gb = (((size_t)(n * Ln + l) * 8 + h) << 7) + cs;
      float4 kv = *(const float4*)(kg + gb);
      float4 vv = *(const float4*)(vg + gb);
      float klv = klg[n * Ln + l];
      float tb = (float)l * invL;
      float ka[4] = {kv.x, kv.y, kv.z, kv.w};
      float va[4] = {vv.x, vv.y, vv.z, vv.w};
#pragma unroll
      for (int e = 0; e < 4; e++) {
        int i = cs + e;
        float kf = (ka[e] > 0.f ? ka[e] + 1.f : __expf(ka[e])) * klv;
        float tt = tb * osb[i];
        float s, c; __sincosf(tt, &s, &c);
        u16 b0 = f2b(kf * c * c), b1 = f2b(kf * s * s), b2 = f2b(kf * s * c);
        size_t nb = ((size_t)nh * Ln + l) * 128 + i;
        kb3[nb] = b0; kb3[nb + NHLD] = b1; kb3[nb + 2 * NHLD] = b2;
        Bu[0][rr][i] = b0; Bu[1][rr][i] = b1; Bu[2][rr][i] = b2; Bu[3][rr][i] = f2b(va[e]);
      }
    }
    __syncthreads();
    for (int idx = t; idx < 1024; idx += 256) {
      int arr = idx >> 8, rem = idx & 255, i = rem >> 1, hf = rem & 1;
      int lc = hf << 4;
      u16 tmp[16];
#pragma unroll
      for (int u = 0; u < 16; u++) tmp[u] = Bu[arr][lc + u][i];
      u16* dst; size_t db;
      if (arr < 3) { dst = kbt3; db = ((size_t)((arr * 32 + nh) * 128 + i)) * Ln + (l0 + ls0 + lc); }
      else         { dst = vt;   db = ((size_t)(nh * 128 + i)) * Ln + (l0 + ls0 + lc); }
      s16x8 p0, p1;
#pragma unroll
      for (int e = 0; e < 8; e++) { p0[e] = (short)tmp[e]; p1[e] = (short)tmp[8 + e]; }
      *(s16x8*)(dst + db) = p0;
      *(s16x8*)(dst + db + 8) = p1;
    }
  }
}

// ---------------- P1a: per-chunk S^T[j][i] = sum_s V[s,j]*Kb[s,i]  (A=Vt rows j, B=KbT rows i) + Ksum
__global__ __launch_bounds__(256) void p1a(const u16* __restrict__ vtg, const u16* __restrict__ kbt3,
                                           u16* __restrict__ sct, float* __restrict__ ksum) {
  __shared__ alignas(16) u16 A[64][136];
  __shared__ alignas(16) u16 B[128][136];
  int bid = blockIdx.x, t = threadIdx.x;
  int half = bid & 1, c = (bid >> 1) & 15, h = (bid >> 5) & 7, n = (bid >> 8) & 3, b = bid >> 10;
  int l0 = c << 7, j0 = half << 6, nh = (n << 3) + h, bnh = b * 32 + nh;
  for (int idx = t; idx < 1024; idx += 256) {
    int j = idx >> 4, cs = (idx & 15) << 3;
    *(s16x8*)&A[j][cs] = *(const s16x8*)(vtg + ((size_t)(nh * 128 + j0 + j)) * Ln + l0 + cs);
  }
  for (int idx = t; idx < 2048; idx += 256) {
    int i = idx >> 4, cs = (idx & 15) << 3;
    *(s16x8*)&B[i][cs] = *(const s16x8*)(kbt3 + ((size_t)(bnh * 128 + i)) * Ln + l0 + cs);
  }
  __syncthreads();
  int lane = t & 63, quad = lane >> 4, nl = lane & 15, w = t >> 6;
  f32x4 z4 = {0.f, 0.f, 0.f, 0.f};
  f32x4 acc[8];
#pragma unroll
  for (int i = 0; i < 8; i++) acc[i] = z4;
  for (int ks = 0; ks < 4; ks++) {
    int k0 = (ks << 5) + (quad << 3);
    s16x8 av = *(const s16x8*)&A[(w << 4) + nl][k0];
#pragma unroll
    for (int ct = 0; ct < 8; ct++) {
      s16x8 bv = *(const s16x8*)&B[(ct << 4) + nl][k0];
      acc[ct] = __builtin_amdgcn_mfma_f32_16x16x32_bf16(av, bv, acc[ct], 0, 0, 0);
    }
  }
  size_t sbase = ((size_t)(bnh * 16 + c)) << 14;
  int lbase = (w << 4) + (quad << 2);
#pragma unroll
  for (int ct = 0; ct < 8; ct++) {
    int i = (ct << 4) + nl;
#pragma unroll
    for (int r = 0; r < 4; r++) {
      int j = j0 + lbase + r;
      sct[sbase + ((size_t)j << 7) + i] = f2b(acc[ct][r]);
    }
  }
  if (half == 0 && t < 128) { // per-chunk K column sums
    float s = 0.f;
    for (int cs = 0; cs < 128; cs += 8) {
      s16x8 v = *(const s16x8*)&B[t][cs];
#pragma unroll
      for (int e = 0; e < 8; e++) s += b2f((u16)v[e]);
    }
    ksum[(size_t)(bnh * 16 + c) * 128 + t] = s;
  }
}

// ---------------- P1b: in-place exclusive prefix over chunks for sct (bf16) and ksum (fp32)
__global__ __launch_bounds__(256) void p1b(u16* __restrict__ sct, float* __restrict__ ksum) {
  int bid = blockIdx.x, t = threadIdx.x;
  if (bid < 6144) {
    size_t m = (size_t)bid * 256 + t;
    int ji = (int)(m & 16383), bnh = (int)(m >> 14);
    size_t base = ((size_t)bnh << 18) + ji;
    float acc = 0.f;
    for (int c = 0; c < 16; c++) {
      size_t a = base + ((size_t)c << 14);
      float v = b2f(sct[a]);
      sct[a] = f2b(acc);
      acc += v;
    }
  } else {
    int m2 = (bid - 6144) * 256 + t;
    int i = m2 & 127, bnh = m2 >> 7;
    size_t base = (size_t)bnh * 2048 + i;
    float acc = 0.f;
    for (int c = 0; c < 16; c++) {
      size_t a = base + (size_t)c * 128;
      float v = ksum[a];
      ksum[a] = acc;
      acc += v;
    }
  }
}

// ---------------- P3: scores (3 branches) + causal mask + intra PV + inter Q*Sprefix + Z, divide
__global__ __launch_bounds__(256) void p3(const u16* __restrict__ qb3, const u16* __restrict__ kb3,
                                          const u16* __restrict__ vtg, const u16* __restrict__ sct,
                                          const float* __restrict__ ksum, float* __restrict__ outg) {
  __shared__ alignas(16) u16 A[64][136];   // Qb tile / later masked P (bf16)
  __shared__ alignas(16) u16 B[128][136];  // Kb / Sprefix^T / V^T
  __shared__ float zint[64], kbuf[128], zfin[64];
  int bid = blockIdx.x, t = threadIdx.x;
  int half = bid & 1, c = (bid >> 1) & 15, h = (bid >> 5) & 7, n = bid >> 8;
  int l0c = c << 7, l0 = l0c + (half << 6), nh = (n << 3) + h;
  int lane = t & 63, quad = lane >> 4, nl = lane & 15, w = t >> 6;
  f32x4 z4 = {0.f, 0.f, 0.f, 0.f};
  f32x4 accP[8], accO[8];
#pragma unroll
  for (int i = 0; i < 8; i++) { accP[i] = z4; accO[i] = z4; }
  if (t < 64) zint[t] = 0.f;
  // ---- loop 1: P += Qb_b * Kb_b^T (K-dim = feature i), summed over branches
  for (int b = 0; b < 3; b++) {
    __syncthreads();
    int bnh = b * 32 + nh;
    for (int idx = t; idx < 1024; idx += 256) {
      int l = idx >> 4, cs = (idx & 15) << 3;
      *(s16x8*)&A[l][cs] = *(const s16x8*)(qb3 + (((size_t)bnh * Ln + l0 + l) << 7) + cs);
    }
    for (int idx = t; idx < 2048; idx += 256) {
      int s = idx >> 4, cs = (idx & 15) << 3;
      *(s16x8*)&B[s][cs] = *(const s16x8*)(kb3 + (((size_t)bnh * Ln + l0c + s) << 7) + cs);
    }
    __syncthreads();
    for (int ks = 0; ks < 4; ks++) {
      int k0 = (ks << 5) + (quad << 3);
      s16x8 av = *(const s16x8*)&A[(w << 4) + nl][k0];
#pragma unroll
      for (int ct = 0; ct < 8; ct++) {
        s16x8 bv = *(const s16x8*)&B[(ct << 4) + nl][k0];
        accP[ct] = __builtin_amdgcn_mfma_f32_16x16x32_bf16(av, bv, accP[ct], 0, 0, 0);
      }
    }
  }
  // ---- loop 2: O += Qb_b * Sprefix_b (B = Sprefix^T rows j, k=i); Z_inter via KsumPrefix
  for (int b = 0; b < 3; b++) {
    __syncthreads();
    int bnh = b * 32 + nh;
    for (int idx = t; idx < 1024; idx += 256) {
      int l = idx >> 4, cs = (idx & 15) << 3;
      *(s16x8*)&A[l][cs] = *(const s16x8*)(qb3 + (((size_t)bnh * Ln + l0 + l) << 7) + cs);
    }
    size_t sbase = ((size_t)(bnh * 16 + c)) << 14;
    for (int idx = t; idx < 2048; idx += 256) {
      int j = idx >> 4, cs = (idx & 15) << 3;
      *(s16x8*)&B[j][cs] = *(const s16x8*)(sct + sbase + ((size_t)j << 7) + cs);
    }
    if (t < 128) kbuf[t] = ksum[(size_t)(bnh * 16 + c) * 128 + t];
    __syncthreads();
    for (int ks = 0; ks < 4; ks++) {
      int k0 = (ks << 5) + (quad << 3);
      s16x8 av = *(const s16x8*)&A[(w << 4) + nl][k0];
#pragma unroll
      for (int ct = 0; ct < 8; ct++) {
        s16x8 bv = *(const s16x8*)&B[(ct << 4) + nl][k0];
        accO[ct] = __builtin_amdgcn_mfma_f32_16x16x32_bf16(av, bv, accO[ct], 0, 0, 0);
      }
    }
    if (t < 64) {
      float z = 0.f;
      for (int cs = 0; cs < 128; cs += 8) {
        s16x8 qv = *(const s16x8*)&A[t][cs];
#pragma unroll
        for (int e = 0; e < 8; e++) z += b2f((u16)qv[e]) * kbuf[cs + e];
      }
      zint[t] += z;
    }
  }
  // ---- intra: mask P (s_local <= half*64 + l_local), store bf16 P into A; stage V^T into B
  __syncthreads();
  {
    int lbase = (w << 4) + (quad << 2);
#pragma unroll
    for (int ct = 0; ct < 8; ct++) {
      int ss = (ct << 4) + nl;
#pragma unroll
      for (int r = 0; r < 4; r++) {
        int lr = lbase + r;
        float pv = (ss <= (half << 6) + lr) ? accP[ct][r] : 0.f;
        A[lr][ss] = f2b(pv);
      }
    }
    for (int idx = t; idx < 2048; idx += 256) {
      int j = idx >> 4, cs = (idx & 15) << 3;
      *(s16x8*)&B[j][cs] = *(const s16x8*)(vtg + ((size_t)(nh * 128 + j)) * Ln + l0c + cs);
    }
  }
  __syncthreads();
  for (int ks = 0; ks < 4; ks++) {
    int k0 = (ks << 5) + (quad << 3);
    s16x8 av = *(const s16x8*)&A[(w << 4) + nl][k0];
#pragma unroll
    for (int ct = 0; ct < 8; ct++) {
      s16x8 bv = *(const s16x8*)&B[(ct << 4) + nl][k0];
      accO[ct] = __builtin_amdgcn_mfma_f32_16x16x32_bf16(av, bv, accO[ct], 0, 0, 0);
    }
  }
  if (t < 64) { // Z = Z_inter + rowsum(masked P) + eps
    float z = 0.f;
    for (int cs = 0; cs < 128; cs += 8) {
      s16x8 pv = *(const s16x8*)&A[t][cs];
#pragma unroll
      for (int e = 0; e < 8; e++) z += b2f((u16)pv[e]);
    }
    zfin[t] = zint[t] + z + 1e-6f;
  }
  __syncthreads();
  {
    int lbase = (w << 4) + (quad << 2);
#pragma unroll
    for (int ct = 0; ct < 8; ct++) {
      int j = (ct << 4) + nl;
#pragma unroll
      for (int r = 0; r < 4; r++) {
        int lr = lbase + r;
        outg[(((size_t)n * Ln + (l0 + lr)) * 8 + h) * 128 + j] = accO[ct][r] / zfin[lr];
      }
    }
  }
}

extern "C" void kernel_launch(void* const* d_in, const int* in_sizes, int n_in,
                              void* d_out, int out_size, void* d_ws, size_t ws_size,
                              hipStream_t stream) {
  (void)in_sizes; (void)n_in; (void)out_size; (void)ws_size;
  const float* q   = (const float*)d_in[0];
  const float* q2  = (const float*)d_in[1];
  const float* kk  = (const float*)d_in[2];
  const float* vv  = (const float*)d_in[3];
  const float* kl  = (const float*)d_in[4];
  const float* om  = (const float*)d_in[5];
  float* out = (float*)d_out;

  // workspace carve (bf16 region then fp32 region) — total ~209 MB
  u16* W     = (u16*)d_ws;
  u16* qb3   = W;                 // 3*NHLD
  u16* kb3   = W + 3 * NHLD;      // 3*NHLD
  u16* kbt3  = W + 6 * NHLD;      // 3*NHLD
  u16* vt    = W + 9 * NHLD;      // NHLD
  u16* sct   = W + 10 * NHLD;     // 3*NHLD (chunk sums -> exclusive prefix, in place)
  u16* wt    = W + 13 * NHLD;     // 131072 (omega^T bf16)
  float* ks  = (float*)(W + 13 * NHLD + 131072); // 196608 f32 (chunk Ksum -> prefix)
  float* osm = ks + 196608;       // 1024 f32

  k_omega <<<8,    256, 0, stream>>>(om, wt, osm);
  k_qfeat <<<1024, 256, 0, stream>>>(q2, q, wt, osm, qb3);
  k_kvfeat<<<512,  256, 0, stream>>>(kk, vv, kl, osm, kb3, kbt3, vt);
  p1a     <<<3072, 256, 0, stream>>>(vt, kbt3, sct, ks);
  p1b     <<<6192, 256, 0, stream>>>(sct, ks);
  p3      <<<1024, 256, 0, stream>>>(qb3, kb3, vt, sct, ks, out);
}